// Round 6
// baseline (115.394 us; speedup 1.0000x reference)
//
#include <hip/hip_runtime.h>
#include <math.h>

// ---------------------------------------------------------------------------
// PCA local frames, single-kernel, round 6: REGISTER-RESIDENT eigensolver.
//
// History of the bottleneck:
//   r4: solver arrays demoted to scratch (dynamic indexing) -> ~200cyc/access
//       on a dependent chain; 46.8us.
//   r5: state in LDS -> ds_read latency ~120cyc single-outstanding on the
//       same dependent chain; only ~41us.  Latency-bound chains need VGPRs.
//   r6: all solver state in scalar registers; every dynamically-indexed
//       access becomes a 2-4-op select/cndmask chain (n=3: d has 3 slots,
//       e 2, work 2, z 9 with rows unrolled -> 3-way column selects).
//       ~4cyc per access instead of 120-200.  NO FP op added/moved/
//       reordered -> output bit-identical to the validated kernels.
//
// Round-3 lesson: no cross-kernel d_ws producer/consumer (graph-replay
// divergence).  Single kernel, LDS only for the edge-vector staging.
//
// Sign-exactness (validated round 2): replicate numpy's CPU ssyevd path:
// SSYTD2(lower) -> SSTEQR('I') -> SLARF1F, OpenBLAS-FMA BLAS tails,
// contract-off everywhere else.  DO NOT change summation order or FMA
// placement — rank-deficient corner nodes are rounding-trajectory-determined.
// ---------------------------------------------------------------------------

#pragma clang fp contract(off)

#define EPS_F32    5.9604645e-8f     /* SLAMCH('E') = 2^-24            */
#define SAFMIN_F32 1.17549435e-38f   /* SLAMCH('S') = 2^-126           */

__device__ __forceinline__ float lapy2f(float x, float y) {
#pragma clang fp contract(off)
  float xa = fabsf(x), ya = fabsf(y);
  float w = fmaxf(xa, ya);
  float z = fminf(xa, ya);
  if (z == 0.0f) return w;
  float t = z / w;
  return w * sqrtf(1.0f + t * t);
}

// LAPACK >= 3.10 slartg (float32).
__device__ __forceinline__ void slartgf(float f, float g, float* c, float* s, float* r) {
#pragma clang fp contract(off)
  const float safmin = SAFMIN_F32;
  const float safmax = 8.50705917e37f;   // 1/safmin
  const float rtmin  = 1.08420217e-19f;  // sqrt(safmin)
  const float rtmax  = 6.52530446e18f;   // sqrt(safmax/2)
  if (g == 0.0f) { *c = 1.0f; *s = 0.0f; *r = f; return; }
  if (f == 0.0f) { *c = 0.0f; *s = copysignf(1.0f, g); *r = fabsf(g); return; }
  float f1 = fabsf(f), g1 = fabsf(g);
  if (f1 > rtmin && f1 < rtmax && g1 > rtmin && g1 < rtmax) {
    float d = sqrtf(f * f + g * g);
    *c = f1 / d;
    *r = copysignf(d, f);
    *s = g / (*r);
  } else {
    float u  = fminf(safmax, fmaxf(safmin, fmaxf(f1, g1)));
    float fs = f / u, gs = g / u;
    float d  = sqrtf(fs * fs + gs * gs);
    *c = fabsf(fs) / d;
    float rr = copysignf(d, f);
    *s = gs / rr;
    *r = rr * u;
  }
}

// LAPACK slaev2 (float32), verbatim transcription.
__device__ __forceinline__ void slaev2f(float a, float b, float c,
                                        float* rt1, float* rt2,
                                        float* cs1, float* sn1) {
#pragma clang fp contract(off)
  float sm  = a + c;
  float df  = a - c;
  float adf = fabsf(df);
  float tb  = b + b;
  float ab  = fabsf(tb);
  float acmx, acmn;
  if (fabsf(a) > fabsf(c)) { acmx = a; acmn = c; } else { acmx = c; acmn = a; }
  float rt;
  if (adf > ab)      { float t = ab / adf; rt = adf * sqrtf(1.0f + t * t); }
  else if (adf < ab) { float t = adf / ab; rt = ab  * sqrtf(1.0f + t * t); }
  else               { rt = ab * sqrtf(2.0f); }
  int sgn1;
  if (sm < 0.0f) {
    *rt1 = 0.5f * (sm - rt); sgn1 = -1;
    *rt2 = (acmx / *rt1) * acmn - (b / *rt1) * b;
  } else if (sm > 0.0f) {
    *rt1 = 0.5f * (sm + rt); sgn1 = 1;
    *rt2 = (acmx / *rt1) * acmn - (b / *rt1) * b;
  } else {
    *rt1 = 0.5f * rt; *rt2 = -0.5f * rt; sgn1 = 1;
  }
  int sgn2; float cs;
  if (df >= 0.0f) { cs = df + rt; sgn2 = 1; }
  else            { cs = df - rt; sgn2 = -1; }
  float acs = fabsf(cs);
  if (acs > ab) {
    float ct = -tb / cs;
    *sn1 = 1.0f / sqrtf(1.0f + ct * ct);
    *cs1 = ct * (*sn1);
  } else {
    if (ab == 0.0f) { *cs1 = 1.0f; *sn1 = 0.0f; }
    else {
      float tn = -cs / tb;
      *cs1 = 1.0f / sqrtf(1.0f + tn * tn);
      *sn1 = tn * (*cs1);
    }
  }
  if (sgn1 == sgn2) { float tn = *cs1; *cs1 = -(*sn1); *sn1 = tn; }
}

// ---------------------------------------------------------------------------
// cov -> frames, ALL state in scalar registers.  Dynamic indices resolved by
// select chains (register-resident; no scratch, no LDS).  Arithmetic is a
// token-identical transcription of the validated LAPACK-replica path.
// ---------------------------------------------------------------------------
__device__ void eig_frames_reg(float c00, float c01, float c02,
                               float c11, float c12, float c22,
                               float* __restrict__ o) {
#pragma clang fp contract(off)
  // ---- SSYTD2, n=3, lower (one Householder), OpenBLAS-FMA BLAS model ----
  float d1, d2, d3, e1, e2, tau1, v2;
  {
    float a11 = c00, a21 = c01, a31 = c02, a22 = c11, a32 = c12, a33 = c22;
    float xnorm = fabsf(a31);
    if (xnorm == 0.0f) {
      tau1 = 0.0f; v2 = 0.0f;
      d1 = a11; d2 = a22; d3 = a33;
      e1 = a21; e2 = a32;
    } else {
      float py2  = lapy2f(a21, xnorm);
      float beta = -copysignf(py2, a21);
      tau1 = (beta - a21) / beta;
      v2   = a31 * (1.0f / (a21 - beta));
      float t2 = a32 * v2;
      float w1 = __builtin_fmaf(tau1, t2, tau1 * a22);
      float w2 = __builtin_fmaf(tau1 * v2, a33, tau1 * a32);
      float dot = __builtin_fmaf(v2, w2, w1);
      float ac = (-0.5f * tau1) * dot;
      w1 = w1 + ac;
      w2 = __builtin_fmaf(ac, v2, w2);
      float A11 = a22 - w1;
      A11 = A11 - w1;
      float A21 = a32 - w2;
      A21 = __builtin_fmaf(-w1, v2, A21);
      float A33 = __builtin_fmaf(-v2, w2, a33);
      A33 = __builtin_fmaf(-w2, v2, A33);
      d1 = a11; d2 = A11; d3 = A33;
      e1 = beta; e2 = A21;
    }
  }

  // ---- SSTEQR('I'), n=3, register-resident ----
  float z11 = 1.0f, z12 = 0.0f, z13 = 0.0f;
  float z21 = 0.0f, z22 = 1.0f, z23 = 0.0f;
  float z31 = 0.0f, z32 = 0.0f, z33 = 1.0f;
  float wc0 = 0.0f, wc1 = 0.0f, ws0 = 0.0f, ws1 = 0.0f;

#define DGET(i)    ((i) == 1 ? d1 : (i) == 2 ? d2 : d3)
#define DSET(i,v)  do { float _t = (v); if ((i) == 1) d1 = _t; else if ((i) == 2) d2 = _t; else d3 = _t; } while (0)
#define EGET(i)    ((i) == 1 ? e1 : e2)
#define ESET(i,v)  do { float _t = (v); if ((i) == 1) e1 = _t; else e2 = _t; } while (0)
#define WCGET(q)   ((q) == 0 ? wc0 : wc1)
#define WCSET(q,v) do { float _t = (v); if ((q) == 0) wc0 = _t; else wc1 = _t; } while (0)
#define WSGET(q)   ((q) == 0 ? ws0 : ws1)
#define WSSET(q,v) do { float _t = (v); if ((q) == 0) ws0 = _t; else ws1 = _t; } while (0)
#define ZGET(r,c)  ((r) == 1 ? ((c) == 1 ? z11 : (c) == 2 ? z12 : z13) \
                  : (r) == 2 ? ((c) == 1 ? z21 : (c) == 2 ? z22 : z23) \
                  :            ((c) == 1 ? z31 : (c) == 2 ? z32 : z33))
#define ZSET(r,c,v) do { float _t = (v); \
    if ((r) == 1)      { if ((c) == 1) z11 = _t; else if ((c) == 2) z12 = _t; else z13 = _t; } \
    else if ((r) == 2) { if ((c) == 1) z21 = _t; else if ((c) == 2) z22 = _t; else z23 = _t; } \
    else               { if ((c) == 1) z31 = _t; else if ((c) == 2) z32 = _t; else z33 = _t; } } while (0)

  {
    const float eps    = EPS_F32;
    const float eps2   = eps * eps;
    const float safmin = SAFMIN_F32;
    const float ssfmax = sqrtf(8.50705917e37f) / 3.0f;
    const float ssfmin = sqrtf(safmin) / eps2;

    int   l1, l, m, lsv, lend, lendsv, iscale;
    const int nmaxit = 90;
    int   jtot = 0;
    float anorm, p, g, r, rt1, rt2, rc, rs, f, b;

    l1 = 1;

L10:
    if (l1 > 3) goto L160;
    if (l1 > 1) ESET(l1 - 1, 0.0f);
    if (l1 <= 2) {
      for (m = l1; m <= 2; m++) {
        float tst = fabsf(EGET(m));
        if (tst == 0.0f) goto L30;
        if (tst <= (sqrtf(fabsf(DGET(m))) * sqrtf(fabsf(DGET(m + 1)))) * eps) {
          ESET(m, 0.0f);
          goto L30;
        }
      }
    }
    m = 3;
L30:
    l = l1; lsv = l; lend = m; lendsv = lend; l1 = m + 1;
    if (lend == l) goto L10;

    // anorm = slanst('M', ...)
    anorm = 0.0f;
    for (int q = l; q <= lend; q++)     anorm = fmaxf(anorm, fabsf(DGET(q)));
    for (int q = l; q <= lend - 1; q++) anorm = fmaxf(anorm, fabsf(EGET(q)));
    iscale = 0;
    if (anorm == 0.0f) goto L10;
    if (anorm > ssfmax) {
      iscale = 1;
      float sc = ssfmax / anorm;
      for (int q = l; q <= lend; q++)     DSET(q, DGET(q) * sc);
      for (int q = l; q <= lend - 1; q++) ESET(q, EGET(q) * sc);
    } else if (anorm < ssfmin) {
      iscale = 2;
      float sc = ssfmin / anorm;
      for (int q = l; q <= lend; q++)     DSET(q, DGET(q) * sc);
      for (int q = l; q <= lend - 1; q++) ESET(q, EGET(q) * sc);
    }

    if (fabsf(DGET(lend)) < fabsf(DGET(l))) { lend = lsv; l = lendsv; }

    if (lend > l) {
      // ---------------- QL iteration ----------------
L40:
      if (l != lend) {
        for (m = l; m <= lend - 1; m++) {
          float tst = EGET(m) * EGET(m);
          if (tst <= (eps2 * fabsf(DGET(m))) * fabsf(DGET(m + 1)) + safmin) goto L60;
        }
      }
      m = lend;
L60:
      if (m < lend) ESET(m, 0.0f);
      p = DGET(l);
      if (m == l) goto L80;
      if (m == l + 1) {
        slaev2f(DGET(l), EGET(l), DGET(l + 1), &rt1, &rt2, &rc, &rs);
        WCSET(l - 1, rc);
        WSSET(l - 1, rs);
        // slasr 'R','V','B', 1 rotation on cols (l, l+1)
        #pragma unroll
        for (int row = 1; row <= 3; row++) {
          float t  = ZGET(row, l + 1);
          float zl = ZGET(row, l);
          ZSET(row, l + 1, rc * t - rs * zl);
          ZSET(row, l,     rs * t + rc * zl);
        }
        DSET(l, rt1); DSET(l + 1, rt2); ESET(l, 0.0f);
        l += 2;
        if (l <= lend) goto L40;
        goto L140;
      }
      if (jtot == nmaxit) goto L140;
      jtot++;
      g = (DGET(l + 1) - p) / (2.0f * EGET(l));
      r = lapy2f(g, 1.0f);
      g = DGET(m) - p + (EGET(l) / (g + copysignf(r, g)));
      rs = 1.0f; rc = 1.0f; p = 0.0f;
      for (int i = m - 1; i >= l; i--) {
        f = rs * EGET(i);
        b = rc * EGET(i);
        slartgf(g, f, &rc, &rs, &r);
        if (i != m - 1) ESET(i + 1, r);
        g = DGET(i + 1) - p;
        r = (DGET(i) - g) * rs + 2.0f * rc * b;
        p = rs * r;
        DSET(i + 1, g + p);
        g = rc * r - b;
        WCSET(i - 1, rc);
        WSSET(i - 1, -rs);
      }
      {
        int mm = m - l + 1;  // slasr 'R','V','B'
        for (int j = mm - 1; j >= 1; j--) {
          float cj = WCGET(l + j - 2);
          float sj = WSGET(l + j - 2);
          if (cj != 1.0f || sj != 0.0f) {
            int col = l + j - 1;
            #pragma unroll
            for (int row = 1; row <= 3; row++) {
              float t  = ZGET(row, col + 1);
              float zc = ZGET(row, col);
              ZSET(row, col + 1, cj * t - sj * zc);
              ZSET(row, col,     sj * t + cj * zc);
            }
          }
        }
      }
      DSET(l, DGET(l) - p);
      ESET(l, g);
      goto L40;
L80:
      DSET(l, p);
      l++;
      if (l <= lend) goto L40;
      goto L140;
    } else {
      // ---------------- QR iteration ----------------
L90:
      if (l != lend) {
        for (m = l; m >= lend + 1; m--) {
          float tst = EGET(m - 1) * EGET(m - 1);
          if (tst <= (eps2 * fabsf(DGET(m))) * fabsf(DGET(m - 1)) + safmin) goto L110;
        }
      }
      m = lend;
L110:
      if (m > lend) ESET(m - 1, 0.0f);
      p = DGET(l);
      if (m == l) goto L130;
      if (m == l - 1) {
        slaev2f(DGET(l - 1), EGET(l - 1), DGET(l), &rt1, &rt2, &rc, &rs);
        WCSET(m - 1, rc);
        WSSET(m - 1, rs);
        // slasr 'R','V','F', 1 rotation on cols (l-1, l)
        #pragma unroll
        for (int row = 1; row <= 3; row++) {
          float t  = ZGET(row, l);
          float zl = ZGET(row, l - 1);
          ZSET(row, l,     rc * t - rs * zl);
          ZSET(row, l - 1, rs * t + rc * zl);
        }
        DSET(l - 1, rt1); DSET(l, rt2); ESET(l - 1, 0.0f);
        l -= 2;
        if (l >= lend) goto L90;
        goto L140;
      }
      if (jtot == nmaxit) goto L140;
      jtot++;
      g = (DGET(l - 1) - p) / (2.0f * EGET(l - 1));
      r = lapy2f(g, 1.0f);
      g = DGET(m) - p + (EGET(l - 1) / (g + copysignf(r, g)));
      rs = 1.0f; rc = 1.0f; p = 0.0f;
      for (int i = m; i <= l - 1; i++) {
        f = rs * EGET(i);
        b = rc * EGET(i);
        slartgf(g, f, &rc, &rs, &r);
        if (i != m) ESET(i - 1, r);
        g = DGET(i) - p;
        r = (DGET(i + 1) - g) * rs + 2.0f * rc * b;
        p = rs * r;
        DSET(i, g + p);
        g = rc * r - b;
        WCSET(i - 1, rc);
        WSSET(i - 1, rs);
      }
      {
        int mm = l - m + 1;  // slasr 'R','V','F'
        for (int j = 1; j <= mm - 1; j++) {
          float cj = WCGET(m + j - 2);
          float sj = WSGET(m + j - 2);
          if (cj != 1.0f || sj != 0.0f) {
            int col = m + j - 1;
            #pragma unroll
            for (int row = 1; row <= 3; row++) {
              float t  = ZGET(row, col + 1);
              float zc = ZGET(row, col);
              ZSET(row, col + 1, cj * t - sj * zc);
              ZSET(row, col,     sj * t + cj * zc);
            }
          }
        }
      }
      DSET(l, DGET(l) - p);
      ESET(l - 1, g);
      goto L90;
L130:
      DSET(l, p);
      l--;
      if (l >= lend) goto L90;
      goto L140;
    }

L140:
    if (iscale == 1) {
      float sc = anorm / ssfmax;
      for (int q = lsv; q <= lendsv; q++)     DSET(q, DGET(q) * sc);
      for (int q = lsv; q <= lendsv - 1; q++) ESET(q, EGET(q) * sc);
    } else if (iscale == 2) {
      float sc = anorm / ssfmin;
      for (int q = lsv; q <= lendsv; q++)     DSET(q, DGET(q) * sc);
      for (int q = lsv; q <= lendsv - 1; q++) ESET(q, EGET(q) * sc);
    }
    if (jtot < nmaxit) goto L10;
    goto L160;

L160:
    // ascending selection sort with column swaps (ssteqr tail, icompz>0)
    for (int ii = 2; ii <= 3; ii++) {
      int i = ii - 1, kk = i;
      p = DGET(i);
      for (int j = ii; j <= 3; j++) {
        if (DGET(j) < p) { kk = j; p = DGET(j); }
      }
      if (kk != i) {
        DSET(kk, DGET(i));
        DSET(i, p);
        #pragma unroll
        for (int row = 1; row <= 3; row++) {
          float t = ZGET(row, i);
          ZSET(row, i, ZGET(row, kk));
          ZSET(row, kk, t);
        }
      }
    }
  }

#undef DGET
#undef DSET
#undef EGET
#undef ESET
#undef WCGET
#undef WCSET
#undef WSGET
#undef WSSET
#undef ZGET
#undef ZSET

  // ---- SORM2R / SLARF1F: rows 2..3 of Z, u = (0, 1, v2) ----
  if (tau1 != 0.0f) {
    {
      float z2 = z21, z3 = z31;
      float w = z2 + z3 * v2;
      float t = tau1 * w;
      z21 = __builtin_fmaf(-tau1, w, z2);
      z31 = __builtin_fmaf(v2, -t, z3);
    }
    {
      float z2 = z22, z3 = z32;
      float w = z2 + z3 * v2;
      float t = tau1 * w;
      z22 = __builtin_fmaf(-tau1, w, z2);
      z32 = __builtin_fmaf(v2, -t, z3);
    }
    {
      float z2 = z23, z3 = z33;
      float w = z2 + z3 * v2;
      float t = tau1 * w;
      z23 = __builtin_fmaf(-tau1, w, z2);
      z33 = __builtin_fmaf(v2, -t, z3);
    }
  }

  // frames = vecs^T
  o[0] = z11; o[1] = z21; o[2] = z31;
  o[3] = z12; o[4] = z22; o[5] = z32;
  o[6] = z13; o[7] = z23; o[8] = z33;
}

// ---------------------------------------------------------------------------
// Tiled single kernel: 256 threads / 64 nodes per block.
//   sev[node*193 + slot*3 + c] : conflict-free both phases.
//   Stage 2: 4 waves x 16 lanes, one node per lane, register-resident solver.
// ---------------------------------------------------------------------------
#define NODES_PER_BLOCK 64
#define NODE_STRIDE     193   /* 64*3 + 1 pad */
#define SOLVER_LANES    16

struct __attribute__((aligned(4))) f3 { float x, y, z; };

__global__ void __launch_bounds__(256)
pca_frames_tiled_kernel(const float* __restrict__ pos,
                        const int*   __restrict__ esrc,
                        const int*   __restrict__ nn,
                        float*       __restrict__ out,
                        int n)
{
#pragma clang fp contract(off)
  __shared__ float sev[NODES_PER_BLOCK * NODE_STRIDE];          // 49408 B

  const int tid   = threadIdx.x;
  const int node0 = blockIdx.x * NODES_PER_BLOCK;

  // ---- Stage 1: cooperative gather of this block's 64*64 edges ----
  const int ebase = blockIdx.x * (NODES_PER_BLOCK * 64);
  #pragma unroll
  for (int q = 0; q < 16; ++q) {
    int eb  = q * 256 + tid;
    int n_b = eb >> 6;          // wave-uniform
    int j   = eb & 63;
    int i   = node0 + n_b;
    int s   = esrc[ebase + eb];
    f3 ps   = *reinterpret_cast<const f3*>(pos + 3 * s);   // packed 12B gather
    // dst pos reads are wave-uniform (broadcast); rounding identical: rn(a-b)
    float dx = ps.x - pos[3 * i + 0];
    float dy = ps.y - pos[3 * i + 1];
    float dz = ps.z - pos[3 * i + 2];
    float* row = sev + n_b * NODE_STRIDE + 3 * j;
    row[0] = dx;
    row[1] = dy;
    row[2] = dz;
  }

  __syncthreads();

  // ---- Stage 2: 4 waves x 16 lanes, one node per lane ----
  const int w = tid >> 6;
  const int l = tid & 63;
  if (l < SOLVER_LANES) {
    int nb = w * SOLVER_LANES + l;   // block-local node 0..63
    int i  = node0 + nb;
    float* o = out + (size_t)i * 9;

    if (nn[i] <= 1) {
      #pragma unroll
      for (int j = 0; j < 9; ++j) o[j] = 0.0f;
      return;
    }

    const float* row = sev + nb * NODE_STRIDE;
    float c00 = 0.0f, c01 = 0.0f, c02 = 0.0f, c11 = 0.0f, c12 = 0.0f, c22 = 0.0f;
    // EXACT sequential edge order, EXACT rounding (validated).
    for (int j = 0; j < 64; ++j) {
      float dx = row[3 * j + 0];
      float dy = row[3 * j + 1];
      float dz = row[3 * j + 2];
      c00 = c00 + dx * dx;
      c01 = c01 + dx * dy;
      c02 = c02 + dx * dz;
      c11 = c11 + dy * dy;
      c12 = c12 + dy * dz;
      c22 = c22 + dz * dz;
    }

    eig_frames_reg(c00, c01, c02, c11, c12, c22, o);
  }
}

// ---------------------------------------------------------------------------
// Fallback (unexpected shapes): validated fused structure, register solver.
// ---------------------------------------------------------------------------
__global__ void __launch_bounds__(64)
pca_frames_fused_kernel(const float* __restrict__ pos,
                        const int*   __restrict__ esrc,
                        const int*   __restrict__ nn,
                        float*       __restrict__ out,
                        int n, int k)
{
#pragma clang fp contract(off)
  int i = blockIdx.x * blockDim.x + threadIdx.x;
  if (i >= n) return;
  float* o = out + (size_t)i * 9;

  if (nn[i] <= 1) {
    #pragma unroll
    for (int j = 0; j < 9; ++j) o[j] = 0.0f;
    return;
  }

  float px = pos[3 * i + 0], py = pos[3 * i + 1], pz = pos[3 * i + 2];
  float c00 = 0.0f, c01 = 0.0f, c02 = 0.0f, c11 = 0.0f, c12 = 0.0f, c22 = 0.0f;
  const int* ep = esrc + (size_t)i * k;
  for (int j = 0; j < k; ++j) {
    int sidx = ep[j];
    float dx = pos[3 * sidx + 0] - px;
    float dy = pos[3 * sidx + 1] - py;
    float dz = pos[3 * sidx + 2] - pz;
    c00 = c00 + dx * dx;
    c01 = c01 + dx * dy;
    c02 = c02 + dx * dz;
    c11 = c11 + dy * dy;
    c12 = c12 + dy * dz;
    c22 = c22 + dz * dz;
  }

  eig_frames_reg(c00, c01, c02, c11, c12, c22, o);
}

extern "C" void kernel_launch(void* const* d_in, const int* in_sizes, int n_in,
                              void* d_out, int out_size, void* d_ws, size_t ws_size,
                              hipStream_t stream) {
  const float* pos  = (const float*)d_in[0];
  const int*   esrc = (const int*)d_in[1];
  // d_in[2] = edge_dst: unused (layout is repeat(arange(n), k) by construction)
  const int*   nn   = (const int*)d_in[3];
  float*       out  = (float*)d_out;

  int n = in_sizes[0] / 3;
  if (n <= 0) return;
  int k = in_sizes[1] / n;

  if (k == 64 && (n % NODES_PER_BLOCK) == 0) {
    hipLaunchKernelGGL(pca_frames_tiled_kernel, dim3(n / NODES_PER_BLOCK),
                       dim3(256), 0, stream, pos, esrc, nn, out, n);
  } else {
    const int block = 64;
    hipLaunchKernelGGL(pca_frames_fused_kernel, dim3((n + block - 1) / block),
                       dim3(block), 0, stream, pos, esrc, nn, out, n, k);
  }
}